// Round 19
// baseline (110.052 us; speedup 1.0000x reference)
//
#include <hip/hip_runtime.h>
#include <hip/hip_bf16.h>

#define TWO_N  8192
#define N_HALF 4096
#define DIMS   256

typedef float f32x4 __attribute__((ext_vector_type(4)));
typedef int   i32x4 __attribute__((ext_vector_type(4)));
typedef int   i32x8 __attribute__((ext_vector_type(8)));

// raw v_exp_f32 (args here are bounded |x| <= ~3, no denormal/range handling needed)
__device__ __forceinline__ float fast_exp2(float x) {
#if __has_builtin(__builtin_amdgcn_exp2f)
    return __builtin_amdgcn_exp2f(x);
#else
    float r; asm("v_exp_f32 %0, %1" : "=v"(r) : "v"(x)); return r;
#endif
}

// MX-scaled fp8 MFMA, K=128, unit scales (E8M0 127 = 2^0). cbsz/blgp = 0 =
// OCP e4m3. Verified R18: compiles, absmax 0.0 at unit scales.
__device__ __forceinline__ f32x4 mfma_mx(i32x8 a, i32x8 b, f32x4 c) {
    return __builtin_amdgcn_mfma_scale_f32_16x16x128_f8f6f4(
        a, b, c, 0 /*cbsz: A=fp8*/, 0 /*blgp: B=fp8*/,
        0, 0x7F /*scale_a = 1.0*/, 0, 0x7F /*scale_b = 1.0*/);
}

// async global->LDS, 16B per lane: LDS dest = wave-uniform base (HW adds
// lane*16), global src = per-lane pointer (guide §5; m97 pattern).
#define GLOAD_LDS16(g, l)                                                      \
    __builtin_amdgcn_global_load_lds(                                          \
        (const __attribute__((address_space(1))) unsigned int*)(g),            \
        (__attribute__((address_space(3))) unsigned int*)(l), 16, 0, 0)

// ---------------------------------------------------------------------------
// Kernel 1: normalize rows of reps = cat([zjs, zis]), pre-scale by
// sqrt(2*log2(e)) so the MFMA dot = (1/TEMP)*log2(e)*sim, quantize to OCP
// fp8 e4m3, and store in CONFLICT-FREE 16x16x128 fragment order.
// Per (16-row group g, kk=k>>7): 2048-B region at ((g*2)+kk)*2048, laid out
// as 128 x 16-B slots: slot = lane + 64*h, lane = quad*16 + row%16 (quad =
// (k%128)>>5), h = (k%32)>>4. So a wave's ds_read_b128 at byte lane*16
// (h=0) and 1024 + lane*16 (h=1) is stride-16 -> zero bank conflicts
// (R18's quad*512+l15*32 layout was a 16-way conflict: 1M SQ_LDS_BANK_CONFLICT).
// Also zeroes out[0] for fin1's atomicAdd.
// ---------------------------------------------------------------------------
__global__ __launch_bounds__(256) void nrm_kernel(const float* __restrict__ zis,
                                                  const float* __restrict__ zjs,
                                                  unsigned char* __restrict__ swz,
                                                  float* __restrict__ out)
{
    if (blockIdx.x == 0 && threadIdx.x == 0) out[0] = 0.f;

    const int tid = threadIdx.x;
    const int l32 = tid & 31;
    const int row = blockIdx.x * 8 + (tid >> 5);
    const int k0  = l32 * 8;

    const float* src = (row < N_HALF) ? (zjs + (size_t)row * DIMS)
                                      : (zis + (size_t)(row - N_HALF) * DIMS);
    const float4 v0 = reinterpret_cast<const float4*>(src + k0)[0];
    const float4 v1 = reinterpret_cast<const float4*>(src + k0 + 4)[0];
    float ss = v0.x * v0.x + v0.y * v0.y + v0.z * v0.z + v0.w * v0.w
             + v1.x * v1.x + v1.y * v1.y + v1.z * v1.z + v1.w * v1.w;
#pragma unroll
    for (int m = 1; m < 32; m <<= 1) ss += __shfl_xor(ss, m, 64);
    // norms ~16 for N(0,1) rows; cosine eps path can never trigger
    const float inv = rsqrtf(ss) * 1.69864360045f;  // * sqrt(2*log2(e))

    // pack 8 scaled values to 8 fp8 bytes (2 ints)
    int w0 = 0, w1 = 0;
    w0 = __builtin_amdgcn_cvt_pk_fp8_f32(v0.x * inv, v0.y * inv, w0, 0);
    w0 = __builtin_amdgcn_cvt_pk_fp8_f32(v0.z * inv, v0.w * inv, w0, 1);
    w1 = __builtin_amdgcn_cvt_pk_fp8_f32(v1.x * inv, v1.y * inv, w1, 0);
    w1 = __builtin_amdgcn_cvt_pk_fp8_f32(v1.z * inv, v1.w * inv, w1, 1);

    // kk = l32>>4, quad = (l32>>2)&3, h = (l32>>1)&1, in-slot off = (l32&1)*8
    const int lane_slot = ((l32 >> 2) & 3) * 16 + (row & 15);
    const size_t byte = (size_t)((row >> 4) * 2 + (l32 >> 4)) * 2048
                      + (size_t)(lane_slot + 64 * ((l32 >> 1) & 1)) * 16
                      + (l32 & 1) * 8;
    int2 o; o.x = w0; o.y = w1;
    *reinterpret_cast<int2*>(swz + byte) = o;
}

// ---------------------------------------------------------------------------
// Kernel 2 (MX-fp8 Gram, K=128, conflict-free LDS): fused scaled-Gram +
// exp2 row sums + diag mask + positive extraction.
// R18 proved MX math correct (absmax 0.0) but its LDS layout caused 16-way
// bank conflicts (1M SQ_LDS_BANK_CONFLICT) that ate the 2x MFMA-rate win.
// This round: half-split layout -> both ds_read_b128 per fragment are
// stride-16 (0 conflicts); bfrag global loads become 2 coalesced 1KB reads.
// Geometry unchanged: tile 512 rows x 256 cols, grid 512 (rg 16 x cs 32) =
// 2 blocks/CU, 8 waves x 64 rows, 4 waves/SIMD (~115 VGPR < 128 cap),
// A panel 64KB in 4 x 16KB chunks (2x16KB LDS dbuf), one vmcnt(0)+barrier
// per chunk. D layout (shape-determined, m121-128): row = wr0 + t*16 + l15
// (B-side), col = c0 + quad*4 + j (A-side).
// ---------------------------------------------------------------------------
__global__ __launch_bounds__(512, 4) void ntx_kernel(const unsigned char* __restrict__ swz,
                                                     float* __restrict__ rowsum_part,
                                                     float* __restrict__ pos_part)
{
    __shared__ unsigned char abuf[2][16384];   // 2 x 16 KB (64-col chunk dbuf)

    const int lane = threadIdx.x & 63;
    const int wave = threadIdx.x >> 6;   // 0..7
    const int l15  = lane & 15;
    const int quad = lane >> 4;

    const int rg   = blockIdx.x & 15;    // 16 row groups of 512
    const int cs   = blockIdx.x >> 4;    // 32 col groups of 256
    const int wr0  = rg * 512 + wave * 64;
    const int p0   = wr0 ^ N_HALF;       // partner-row window (positives)

    // stage chunk c (64 cols = 4 col-16-groups x 4096 B = 16KB): 2 x 1KB
    // issues per wave (byte-copy; the fragment permutation lives inside).
    auto stage = [&](int buf, int c) {
        const unsigned char* gsrc = swz + (size_t)cs * 65536 + (size_t)c * 16384
                                  + wave * 2048 + lane * 16;
        GLOAD_LDS16(gsrc,        &abuf[buf][wave * 2048]);
        GLOAD_LDS16(gsrc + 1024, &abuf[buf][wave * 2048 + 1024]);
    };

    stage(0, 0);   // chunk 0 in flight while B fragments load

    // Hoist B (row) fragments: 4 groups of 16 rows x 2 K-chunks (K=128 each).
    // Half-split layout: halves at lane*16 and 1024 + lane*16 -> two
    // coalesced 1KB wave reads per (t,kk). 64 VGPR total.
    i32x8 bfrag[4][2];
#pragma unroll
    for (int t = 0; t < 4; ++t) {
        const unsigned char* bp = swz + (size_t)(((wr0 >> 4) + t) * 2) * 2048 + lane * 16;
#pragma unroll
        for (int kk = 0; kk < 2; ++kk) {
            const i32x4 lo = *reinterpret_cast<const i32x4*>(bp + kk * 2048);
            const i32x4 hi = *reinterpret_cast<const i32x4*>(bp + kk * 2048 + 1024);
            i32x8 r;
            r[0] = lo[0]; r[1] = lo[1]; r[2] = lo[2]; r[3] = lo[3];
            r[4] = hi[0]; r[5] = hi[1]; r[6] = hi[2]; r[7] = hi[3];
            bfrag[t][kk] = r;
        }
    }

    float sum_exp[4] = {0.f, 0.f, 0.f, 0.f};
    float pos_acc = 0.f;

    asm volatile("s_waitcnt vmcnt(0)" ::: "memory");
    __syncthreads();   // chunk 0 resident

    int cur = 0;
    for (int c = 0; c < 4; ++c) {
        if (c < 3) stage(cur ^ 1, c + 1);   // prefetch next chunk (lands early)

        const int cc_base = cs * 256 + c * 64;

#pragma unroll
        for (int it = 0; it < 4; ++it) {    // 4 sub-its of 16 cols
            const unsigned char* ab = &abuf[cur][it * 4096 + lane * 16];
            i32x8 a0, a1;
            {
                const i32x4 lo0 = *reinterpret_cast<const i32x4*>(ab);
                const i32x4 hi0 = *reinterpret_cast<const i32x4*>(ab + 1024);
                const i32x4 lo1 = *reinterpret_cast<const i32x4*>(ab + 2048);
                const i32x4 hi1 = *reinterpret_cast<const i32x4*>(ab + 3072);
                a0[0]=lo0[0]; a0[1]=lo0[1]; a0[2]=lo0[2]; a0[3]=lo0[3];
                a0[4]=hi0[0]; a0[5]=hi0[1]; a0[6]=hi0[2]; a0[7]=hi0[3];
                a1[0]=lo1[0]; a1[1]=lo1[1]; a1[2]=lo1[2]; a1[3]=lo1[3];
                a1[4]=hi1[0]; a1[5]=hi1[1]; a1[6]=hi1[2]; a1[7]=hi1[3];
            }

            f32x4 acc[4] = {{0.f, 0.f, 0.f, 0.f}, {0.f, 0.f, 0.f, 0.f},
                            {0.f, 0.f, 0.f, 0.f}, {0.f, 0.f, 0.f, 0.f}};
#pragma unroll
            for (int t = 0; t < 4; ++t)
                acc[t] = mfma_mx(a0, bfrag[t][0], acc[t]);
#pragma unroll
            for (int t = 0; t < 4; ++t)
                acc[t] = mfma_mx(a1, bfrag[t][1], acc[t]);

            const int c0 = cc_base + it * 16;
            const bool special = (c0 < wr0 + 64 && c0 + 16 > wr0) ||
                                 (c0 < p0 + 64 && c0 + 16 > p0);
            if (!special) {
#pragma unroll
                for (int t = 0; t < 4; ++t)
#pragma unroll
                    for (int j = 0; j < 4; ++j)
                        sum_exp[t] += fast_exp2(acc[t][j]);
            } else {
#pragma unroll
                for (int t = 0; t < 4; ++t) {
                    const int r = wr0 + t * 16 + l15;
#pragma unroll
                    for (int j = 0; j < 4; ++j) {
                        const int col = c0 + quad * 4 + j;
                        const float e = fast_exp2(acc[t][j]);
                        sum_exp[t] += (col == r) ? 0.f : e;               // self-diag
                        if (col == (r ^ N_HALF)) pos_acc += acc[t][j];    // positive
                    }
                }
            }
        }

        // next chunk's loads were issued a full chunk ago -> drain ~free.
        asm volatile("s_waitcnt vmcnt(0)" ::: "memory");
        __syncthreads();
        cur ^= 1;
    }

    // Per-row partial: reduce over the 4 quads (col groups), one store per row.
#pragma unroll
    for (int t = 0; t < 4; ++t) {
        float s = sum_exp[t];
        s += __shfl_xor(s, 16, 64);
        s += __shfl_xor(s, 32, 64);
        if (lane < 16)
            rowsum_part[(size_t)cs * TWO_N + wr0 + t * 16 + lane] = s;
    }

    // Positive partial: every wave writes its slot (0 if no partner overlap).
#pragma unroll
    for (int m = 1; m < 64; m <<= 1) pos_acc += __shfl_xor(pos_acc, m, 64);
    if (lane == 0) pos_part[blockIdx.x * 8 + wave] = pos_acc;
}

// ---------------------------------------------------------------------------
// Kernel 3: per-row ln(sum of 32 partials) minus ln2 * positive partials
// (4096 pos slots; slot->row mapping irrelevant for the global sum),
// block-reduced, one atomicAdd per block onto out[0] (zeroed by nrm).
// ---------------------------------------------------------------------------
__global__ __launch_bounds__(1024) void fin1_kernel(const float* __restrict__ rowsum_part,
                                                    const float* __restrict__ pos_part,
                                                    float* __restrict__ out)
{
    __shared__ float red[16];
    const int t = threadIdx.x;
    const int r = blockIdx.x * 1024 + t;
    float acc = 0.f;
#pragma unroll
    for (int cs = 0; cs < 32; ++cs)
        acc += rowsum_part[(size_t)cs * TWO_N + r];
    float v = logf(acc);
    if (r < 4096)
        v -= 0.69314718055994531f * pos_part[r];
#pragma unroll
    for (int m = 1; m < 64; m <<= 1) v += __shfl_xor(v, m, 64);
    if ((t & 63) == 0) red[t >> 6] = v;
    __syncthreads();
    if (t == 0) {
        float s = 0.f;
#pragma unroll
        for (int w = 0; w < 16; ++w) s += red[w];
        atomicAdd(out, s / (float)TWO_N);
    }
}

// ---------------------------------------------------------------------------
extern "C" void kernel_launch(void* const* d_in, const int* in_sizes, int n_in,
                              void* d_out, int out_size, void* d_ws, size_t ws_size,
                              hipStream_t stream)
{
    const float* zis = (const float*)d_in[0];
    const float* zjs = (const float*)d_in[1];

    // ws: [0,2MB) swizzled fp8; then rowsum partials [32][8192] f32 (1MB);
    //     then pos partials [4096].
    unsigned char* swz = (unsigned char*)d_ws;
    float* rowsum_part = (float*)((char*)d_ws + (size_t)TWO_N * DIMS);
    float* pos_part    = rowsum_part + (size_t)32 * TWO_N;

    nrm_kernel<<<TWO_N / 8, 256, 0, stream>>>(zis, zjs, swz, (float*)d_out);
    ntx_kernel<<<512, 512, 0, stream>>>(swz, rowsum_part, pos_part);
    fin1_kernel<<<8, 1024, 0, stream>>>(rowsum_part, pos_part, (float*)d_out);
}

// Round 20
// 83.744 us; speedup vs baseline: 1.3142x; 1.3142x over previous
//
#include <hip/hip_runtime.h>
#include <hip/hip_bf16.h>

#define TWO_N  8192
#define N_HALF 4096
#define DIMS   256

typedef float f32x4 __attribute__((ext_vector_type(4)));
typedef int   i32x4 __attribute__((ext_vector_type(4)));
typedef int   i32x8 __attribute__((ext_vector_type(8)));

// raw v_exp_f32 (args here are bounded |x| <= ~3, no denormal/range handling needed)
__device__ __forceinline__ float fast_exp2(float x) {
#if __has_builtin(__builtin_amdgcn_exp2f)
    return __builtin_amdgcn_exp2f(x);
#else
    float r; asm("v_exp_f32 %0, %1" : "=v"(r) : "v"(x)); return r;
#endif
}

// MX-scaled fp8 MFMA, K=128, unit scales (E8M0 127 = 2^0). cbsz/blgp = 0 =
// OCP e4m3. Verified R18/R19: compiles, absmax 0.0 at unit scales.
__device__ __forceinline__ f32x4 mfma_mx(i32x8 a, i32x8 b, f32x4 c) {
    return __builtin_amdgcn_mfma_scale_f32_16x16x128_f8f6f4(
        a, b, c, 0 /*cbsz: A=fp8*/, 0 /*blgp: B=fp8*/,
        0, 0x7F /*scale_a = 1.0*/, 0, 0x7F /*scale_b = 1.0*/);
}

// async global->LDS, 16B per lane: LDS dest = wave-uniform base (HW adds
// lane*16), global src = per-lane pointer (guide §5; m97 pattern).
#define GLOAD_LDS16(g, l)                                                      \
    __builtin_amdgcn_global_load_lds(                                          \
        (const __attribute__((address_space(1))) unsigned int*)(g),            \
        (__attribute__((address_space(3))) unsigned int*)(l), 16, 0, 0)

// ---------------------------------------------------------------------------
// Kernel 1: normalize rows of reps = cat([zjs, zis]), pre-scale by
// sqrt(2*log2(e)) so the MFMA dot = (1/TEMP)*log2(e)*sim, quantize to OCP
// fp8 e4m3, and store in CONFLICT-FREE 16x16x128 fragment order (R19 layout,
// verified 0 bank conflicts):
// Per (16-row group g, kk=k>>7): 2048-B region at ((g*2)+kk)*2048, laid out
// as 128 x 16-B slots: slot = lane + 64*h, lane = quad*16 + row%16 (quad =
// (k%128)>>5), h = (k%32)>>4 -> a wave's two ds_read_b128 (lane*16 and
// 1024 + lane*16) are stride-16, conflict-free.
// Also zeroes out[0] for fin1's atomicAdd.
// ---------------------------------------------------------------------------
__global__ __launch_bounds__(256) void nrm_kernel(const float* __restrict__ zis,
                                                  const float* __restrict__ zjs,
                                                  unsigned char* __restrict__ swz,
                                                  float* __restrict__ out)
{
    if (blockIdx.x == 0 && threadIdx.x == 0) out[0] = 0.f;

    const int tid = threadIdx.x;
    const int l32 = tid & 31;
    const int row = blockIdx.x * 8 + (tid >> 5);
    const int k0  = l32 * 8;

    const float* src = (row < N_HALF) ? (zjs + (size_t)row * DIMS)
                                      : (zis + (size_t)(row - N_HALF) * DIMS);
    const float4 v0 = reinterpret_cast<const float4*>(src + k0)[0];
    const float4 v1 = reinterpret_cast<const float4*>(src + k0 + 4)[0];
    float ss = v0.x * v0.x + v0.y * v0.y + v0.z * v0.z + v0.w * v0.w
             + v1.x * v1.x + v1.y * v1.y + v1.z * v1.z + v1.w * v1.w;
#pragma unroll
    for (int m = 1; m < 32; m <<= 1) ss += __shfl_xor(ss, m, 64);
    // norms ~16 for N(0,1) rows; cosine eps path can never trigger
    const float inv = rsqrtf(ss) * 1.69864360045f;  // * sqrt(2*log2(e))

    // pack 8 scaled values to 8 fp8 bytes (2 ints)
    int w0 = 0, w1 = 0;
    w0 = __builtin_amdgcn_cvt_pk_fp8_f32(v0.x * inv, v0.y * inv, w0, 0);
    w0 = __builtin_amdgcn_cvt_pk_fp8_f32(v0.z * inv, v0.w * inv, w0, 1);
    w1 = __builtin_amdgcn_cvt_pk_fp8_f32(v1.x * inv, v1.y * inv, w1, 0);
    w1 = __builtin_amdgcn_cvt_pk_fp8_f32(v1.z * inv, v1.w * inv, w1, 1);

    // kk = l32>>4, quad = (l32>>2)&3, h = (l32>>1)&1, in-slot off = (l32&1)*8
    const int lane_slot = ((l32 >> 2) & 3) * 16 + (row & 15);
    const size_t byte = (size_t)((row >> 4) * 2 + (l32 >> 4)) * 2048
                      + (size_t)(lane_slot + 64 * ((l32 >> 1) & 1)) * 16
                      + (l32 & 1) * 8;
    int2 o; o.x = w0; o.y = w1;
    *reinterpret_cast<int2*>(swz + byte) = o;
}

// ---------------------------------------------------------------------------
// Kernel 2 (MX-fp8 Gram, conflict-free LDS, FULL register budget): fused
// scaled-Gram + exp2 row sums + diag mask + positive extraction.
// R18/R19 post-mortem: BOTH MX rounds ran with VGPR_Count=64 + 24-35MB
// scratch writes -- __launch_bounds__(512,4)'s 128-reg cap split 64 VGPR /
// 64 AGPR and the MFMA *inputs* (bfrag 64 + a 16) spilled out of the arch
// half. Fix: __launch_bounds__(512) = 2 waves/SIMD, 256-reg budget (the
// config that ran R8/R12 spill-free at ~245 live; this kernel's live set is
// ~150). Keep R19's conflict-free half-split layout (verified 0 conflicts).
// Geometry: tile 512 rows x 256 cols, grid 512 (rg 16 x cs 32), 1 block/CU
// resident (streams 2 rounds), 8 waves x 64 rows, A panel 64KB in 4 x 16KB
// chunks (2x16KB LDS dbuf), one vmcnt(0)+barrier per chunk.
// D layout (shape-determined, m121-128): row = wr0 + t*16 + l15 (B-side),
// col = c0 + quad*4 + j (A-side).
// ---------------------------------------------------------------------------
__global__ __launch_bounds__(512) void ntx_kernel(const unsigned char* __restrict__ swz,
                                                  float* __restrict__ rowsum_part,
                                                  float* __restrict__ pos_part)
{
    __shared__ unsigned char abuf[2][16384];   // 2 x 16 KB (64-col chunk dbuf)

    const int lane = threadIdx.x & 63;
    const int wave = threadIdx.x >> 6;   // 0..7
    const int l15  = lane & 15;
    const int quad = lane >> 4;

    const int rg   = blockIdx.x & 15;    // 16 row groups of 512
    const int cs   = blockIdx.x >> 4;    // 32 col groups of 256
    const int wr0  = rg * 512 + wave * 64;
    const int p0   = wr0 ^ N_HALF;       // partner-row window (positives)

    // stage chunk c (64 cols = 4 col-16-groups x 4096 B = 16KB): 2 x 1KB
    // issues per wave (byte-copy; the fragment permutation lives inside).
    auto stage = [&](int buf, int c) {
        const unsigned char* gsrc = swz + (size_t)cs * 65536 + (size_t)c * 16384
                                  + wave * 2048 + lane * 16;
        GLOAD_LDS16(gsrc,        &abuf[buf][wave * 2048]);
        GLOAD_LDS16(gsrc + 1024, &abuf[buf][wave * 2048 + 1024]);
    };

    stage(0, 0);   // chunk 0 in flight while B fragments load

    // Hoist B (row) fragments: 4 groups of 16 rows x 2 K-chunks (K=128 each).
    // Half-split layout -> two coalesced 1KB wave reads per (t,kk); concat
    // via shufflevector (register-pair coalescing, no scratch).
    i32x8 bfrag[4][2];
#pragma unroll
    for (int t = 0; t < 4; ++t) {
        const unsigned char* bp = swz + (size_t)(((wr0 >> 4) + t) * 2) * 2048 + lane * 16;
#pragma unroll
        for (int kk = 0; kk < 2; ++kk) {
            const i32x4 lo = *reinterpret_cast<const i32x4*>(bp + kk * 2048);
            const i32x4 hi = *reinterpret_cast<const i32x4*>(bp + kk * 2048 + 1024);
            bfrag[t][kk] = __builtin_shufflevector(lo, hi, 0, 1, 2, 3, 4, 5, 6, 7);
        }
    }

    float sum_exp[4] = {0.f, 0.f, 0.f, 0.f};
    float pos_acc = 0.f;

    asm volatile("s_waitcnt vmcnt(0)" ::: "memory");
    __syncthreads();   // chunk 0 resident

    int cur = 0;
    for (int c = 0; c < 4; ++c) {
        if (c < 3) stage(cur ^ 1, c + 1);   // prefetch next chunk (lands early)

        const int cc_base = cs * 256 + c * 64;

#pragma unroll
        for (int it = 0; it < 4; ++it) {    // 4 sub-its of 16 cols
            const unsigned char* ab = &abuf[cur][it * 4096 + lane * 16];
            const i32x4 lo0 = *reinterpret_cast<const i32x4*>(ab);
            const i32x4 hi0 = *reinterpret_cast<const i32x4*>(ab + 1024);
            const i32x4 lo1 = *reinterpret_cast<const i32x4*>(ab + 2048);
            const i32x4 hi1 = *reinterpret_cast<const i32x4*>(ab + 3072);
            const i32x8 a0 = __builtin_shufflevector(lo0, hi0, 0, 1, 2, 3, 4, 5, 6, 7);
            const i32x8 a1 = __builtin_shufflevector(lo1, hi1, 0, 1, 2, 3, 4, 5, 6, 7);

            f32x4 acc[4] = {{0.f, 0.f, 0.f, 0.f}, {0.f, 0.f, 0.f, 0.f},
                            {0.f, 0.f, 0.f, 0.f}, {0.f, 0.f, 0.f, 0.f}};
#pragma unroll
            for (int t = 0; t < 4; ++t)
                acc[t] = mfma_mx(a0, bfrag[t][0], acc[t]);
#pragma unroll
            for (int t = 0; t < 4; ++t)
                acc[t] = mfma_mx(a1, bfrag[t][1], acc[t]);

            const int c0 = cc_base + it * 16;
            const bool special = (c0 < wr0 + 64 && c0 + 16 > wr0) ||
                                 (c0 < p0 + 64 && c0 + 16 > p0);
            if (!special) {
#pragma unroll
                for (int t = 0; t < 4; ++t)
#pragma unroll
                    for (int j = 0; j < 4; ++j)
                        sum_exp[t] += fast_exp2(acc[t][j]);
            } else {
#pragma unroll
                for (int t = 0; t < 4; ++t) {
                    const int r = wr0 + t * 16 + l15;
#pragma unroll
                    for (int j = 0; j < 4; ++j) {
                        const int col = c0 + quad * 4 + j;
                        const float e = fast_exp2(acc[t][j]);
                        sum_exp[t] += (col == r) ? 0.f : e;               // self-diag
                        if (col == (r ^ N_HALF)) pos_acc += acc[t][j];    // positive
                    }
                }
            }
        }

        // next chunk's loads were issued a full chunk ago -> drain ~free.
        asm volatile("s_waitcnt vmcnt(0)" ::: "memory");
        __syncthreads();
        cur ^= 1;
    }

    // Per-row partial: reduce over the 4 quads (col groups), one store per row.
#pragma unroll
    for (int t = 0; t < 4; ++t) {
        float s = sum_exp[t];
        s += __shfl_xor(s, 16, 64);
        s += __shfl_xor(s, 32, 64);
        if (lane < 16)
            rowsum_part[(size_t)cs * TWO_N + wr0 + t * 16 + lane] = s;
    }

    // Positive partial: every wave writes its slot (0 if no partner overlap).
#pragma unroll
    for (int m = 1; m < 64; m <<= 1) pos_acc += __shfl_xor(pos_acc, m, 64);
    if (lane == 0) pos_part[blockIdx.x * 8 + wave] = pos_acc;
}

// ---------------------------------------------------------------------------
// Kernel 3: per-row ln(sum of 32 partials) minus ln2 * positive partials
// (4096 pos slots; slot->row mapping irrelevant for the global sum),
// block-reduced, one atomicAdd per block onto out[0] (zeroed by nrm).
// ---------------------------------------------------------------------------
__global__ __launch_bounds__(1024) void fin1_kernel(const float* __restrict__ rowsum_part,
                                                    const float* __restrict__ pos_part,
                                                    float* __restrict__ out)
{
    __shared__ float red[16];
    const int t = threadIdx.x;
    const int r = blockIdx.x * 1024 + t;
    float acc = 0.f;
#pragma unroll
    for (int cs = 0; cs < 32; ++cs)
        acc += rowsum_part[(size_t)cs * TWO_N + r];
    float v = logf(acc);
    if (r < 4096)
        v -= 0.69314718055994531f * pos_part[r];
#pragma unroll
    for (int m = 1; m < 64; m <<= 1) v += __shfl_xor(v, m, 64);
    if ((t & 63) == 0) red[t >> 6] = v;
    __syncthreads();
    if (t == 0) {
        float s = 0.f;
#pragma unroll
        for (int w = 0; w < 16; ++w) s += red[w];
        atomicAdd(out, s / (float)TWO_N);
    }
}

// ---------------------------------------------------------------------------
extern "C" void kernel_launch(void* const* d_in, const int* in_sizes, int n_in,
                              void* d_out, int out_size, void* d_ws, size_t ws_size,
                              hipStream_t stream)
{
    const float* zis = (const float*)d_in[0];
    const float* zjs = (const float*)d_in[1];

    // ws: [0,2MB) swizzled fp8; then rowsum partials [32][8192] f32 (1MB);
    //     then pos partials [4096].
    unsigned char* swz = (unsigned char*)d_ws;
    float* rowsum_part = (float*)((char*)d_ws + (size_t)TWO_N * DIMS);
    float* pos_part    = rowsum_part + (size_t)32 * TWO_N;

    nrm_kernel<<<TWO_N / 8, 256, 0, stream>>>(zis, zjs, swz, (float*)d_out);
    ntx_kernel<<<512, 512, 0, stream>>>(swz, rowsum_part, pos_part);
    fin1_kernel<<<8, 1024, 0, stream>>>(rowsum_part, pos_part, (float*)d_out);
}

// Round 21
// 81.125 us; speedup vs baseline: 1.3566x; 1.0323x over previous
//
#include <hip/hip_runtime.h>
#include <hip/hip_bf16.h>

#define TWO_N  8192
#define N_HALF 4096
#define DIMS   256

typedef float f32x4 __attribute__((ext_vector_type(4)));
typedef int   i32x4 __attribute__((ext_vector_type(4)));
typedef int   i32x8 __attribute__((ext_vector_type(8)));

// raw v_exp_f32 (args here are bounded |x| <= ~3, no denormal/range handling needed)
__device__ __forceinline__ float fast_exp2(float x) {
#if __has_builtin(__builtin_amdgcn_exp2f)
    return __builtin_amdgcn_exp2f(x);
#else
    float r; asm("v_exp_f32 %0, %1" : "=v"(r) : "v"(x)); return r;
#endif
}

// MX-scaled fp8 MFMA, K=128, unit scales (E8M0 127 = 2^0). cbsz/blgp = 0 =
// OCP e4m3. Verified R18-R20: compiles, absmax 0.0, spill-free at
// __launch_bounds__(512) (R20: 83.7us total, best).
__device__ __forceinline__ f32x4 mfma_mx(i32x8 a, i32x8 b, f32x4 c) {
    return __builtin_amdgcn_mfma_scale_f32_16x16x128_f8f6f4(
        a, b, c, 0 /*cbsz: A=fp8*/, 0 /*blgp: B=fp8*/,
        0, 0x7F /*scale_a = 1.0*/, 0, 0x7F /*scale_b = 1.0*/);
}

// async global->LDS, 16B per lane: LDS dest = wave-uniform base (HW adds
// lane*16), global src = per-lane pointer (guide §5; m97 pattern).
#define GLOAD_LDS16(g, l)                                                      \
    __builtin_amdgcn_global_load_lds(                                          \
        (const __attribute__((address_space(1))) unsigned int*)(g),            \
        (__attribute__((address_space(3))) unsigned int*)(l), 16, 0, 0)

// ---------------------------------------------------------------------------
// Kernel 1: normalize rows of reps = cat([zjs, zis]), pre-scale by
// sqrt(2*log2(e)) so the MFMA dot = (1/TEMP)*log2(e)*sim, quantize to OCP
// fp8 e4m3, and store in CONFLICT-FREE 16x16x128 fragment order (R19/R20
// layout, verified 0 bank conflicts):
// Per (16-row group g, kk=k>>7): 2048-B region at ((g*2)+kk)*2048, laid out
// as 128 x 16-B slots: slot = lane + 64*h, lane = quad*16 + row%16 (quad =
// (k%128)>>5), h = (k%32)>>4 -> a wave's two ds_read_b128 (lane*16 and
// 1024 + lane*16) are stride-16, conflict-free.
// Also zeroes out[0] for fin1's atomicAdd.
// ---------------------------------------------------------------------------
__global__ __launch_bounds__(256) void nrm_kernel(const float* __restrict__ zis,
                                                  const float* __restrict__ zjs,
                                                  unsigned char* __restrict__ swz,
                                                  float* __restrict__ out)
{
    if (blockIdx.x == 0 && threadIdx.x == 0) out[0] = 0.f;

    const int tid = threadIdx.x;
    const int l32 = tid & 31;
    const int row = blockIdx.x * 8 + (tid >> 5);
    const int k0  = l32 * 8;

    const float* src = (row < N_HALF) ? (zjs + (size_t)row * DIMS)
                                      : (zis + (size_t)(row - N_HALF) * DIMS);
    const float4 v0 = reinterpret_cast<const float4*>(src + k0)[0];
    const float4 v1 = reinterpret_cast<const float4*>(src + k0 + 4)[0];
    float ss = v0.x * v0.x + v0.y * v0.y + v0.z * v0.z + v0.w * v0.w
             + v1.x * v1.x + v1.y * v1.y + v1.z * v1.z + v1.w * v1.w;
#pragma unroll
    for (int m = 1; m < 32; m <<= 1) ss += __shfl_xor(ss, m, 64);
    // norms ~16 for N(0,1) rows; cosine eps path can never trigger
    const float inv = rsqrtf(ss) * 1.69864360045f;  // * sqrt(2*log2(e))

    // pack 8 scaled values to 8 fp8 bytes (2 ints)
    int w0 = 0, w1 = 0;
    w0 = __builtin_amdgcn_cvt_pk_fp8_f32(v0.x * inv, v0.y * inv, w0, 0);
    w0 = __builtin_amdgcn_cvt_pk_fp8_f32(v0.z * inv, v0.w * inv, w0, 1);
    w1 = __builtin_amdgcn_cvt_pk_fp8_f32(v1.x * inv, v1.y * inv, w1, 0);
    w1 = __builtin_amdgcn_cvt_pk_fp8_f32(v1.z * inv, v1.w * inv, w1, 1);

    // kk = l32>>4, quad = (l32>>2)&3, h = (l32>>1)&1, in-slot off = (l32&1)*8
    const int lane_slot = ((l32 >> 2) & 3) * 16 + (row & 15);
    const size_t byte = (size_t)((row >> 4) * 2 + (l32 >> 4)) * 2048
                      + (size_t)(lane_slot + 64 * ((l32 >> 1) & 1)) * 16
                      + (l32 & 1) * 8;
    int2 o; o.x = w0; o.y = w1;
    *reinterpret_cast<int2*>(swz + byte) = o;
}

// ---------------------------------------------------------------------------
// Kernel 2 (MX-fp8 Gram, SINGLE dispatch round): fused scaled-Gram + exp2
// row sums + diag mask + positive extraction.
// CHANGE vs R20 (83.7us best): tile widened 512x256 -> 512x512 (8 chunks of
// 64 cols instead of 4), grid 512 -> 256 = exactly 1 block/CU, ONE round.
// R20's grid-512 at 1 resident block/CU ran 2 sequential rounds, paying the
// prologue (16KB bfrag global loads + first stage + barrier) twice plus an
// inter-round gap. Steady-state loop, LDS layout (conflict-free half-split),
// staging, register budget (__launch_bounds__(512), 256 regs, spill-free in
// R20) all byte-identical. fin1 now sums 16 slots (was 32).
// D layout (shape-determined, m121-128): row = wr0 + t*16 + l15 (B-side),
// col = c0 + quad*4 + j (A-side).
// ---------------------------------------------------------------------------
__global__ __launch_bounds__(512) void ntx_kernel(const unsigned char* __restrict__ swz,
                                                  float* __restrict__ rowsum_part,
                                                  float* __restrict__ pos_part)
{
    __shared__ unsigned char abuf[2][16384];   // 2 x 16 KB (64-col chunk dbuf)

    const int lane = threadIdx.x & 63;
    const int wave = threadIdx.x >> 6;   // 0..7
    const int l15  = lane & 15;
    const int quad = lane >> 4;

    const int rg   = blockIdx.x & 15;    // 16 row groups of 512
    const int cs   = blockIdx.x >> 4;    // 16 col groups of 512
    const int wr0  = rg * 512 + wave * 64;
    const int p0   = wr0 ^ N_HALF;       // partner-row window (positives)

    // stage chunk c (64 cols = 4 col-16-groups x 4096 B = 16KB): 2 x 1KB
    // issues per wave (byte-copy; the fragment permutation lives inside).
    auto stage = [&](int buf, int c) {
        const unsigned char* gsrc = swz + (size_t)cs * 131072 + (size_t)c * 16384
                                  + wave * 2048 + lane * 16;
        GLOAD_LDS16(gsrc,        &abuf[buf][wave * 2048]);
        GLOAD_LDS16(gsrc + 1024, &abuf[buf][wave * 2048 + 1024]);
    };

    stage(0, 0);   // chunk 0 in flight while B fragments load

    // Hoist B (row) fragments: 4 groups of 16 rows x 2 K-chunks (K=128 each).
    // Half-split layout -> two coalesced 1KB wave reads per (t,kk); concat
    // via shufflevector (register-pair coalescing, no scratch).
    i32x8 bfrag[4][2];
#pragma unroll
    for (int t = 0; t < 4; ++t) {
        const unsigned char* bp = swz + (size_t)(((wr0 >> 4) + t) * 2) * 2048 + lane * 16;
#pragma unroll
        for (int kk = 0; kk < 2; ++kk) {
            const i32x4 lo = *reinterpret_cast<const i32x4*>(bp + kk * 2048);
            const i32x4 hi = *reinterpret_cast<const i32x4*>(bp + kk * 2048 + 1024);
            bfrag[t][kk] = __builtin_shufflevector(lo, hi, 0, 1, 2, 3, 4, 5, 6, 7);
        }
    }

    float sum_exp[4] = {0.f, 0.f, 0.f, 0.f};
    float pos_acc = 0.f;

    asm volatile("s_waitcnt vmcnt(0)" ::: "memory");
    __syncthreads();   // chunk 0 resident

    int cur = 0;
    for (int c = 0; c < 8; ++c) {
        if (c < 7) stage(cur ^ 1, c + 1);   // prefetch next chunk (lands early)

        const int cc_base = cs * 512 + c * 64;

#pragma unroll
        for (int it = 0; it < 4; ++it) {    // 4 sub-its of 16 cols
            const unsigned char* ab = &abuf[cur][it * 4096 + lane * 16];
            const i32x4 lo0 = *reinterpret_cast<const i32x4*>(ab);
            const i32x4 hi0 = *reinterpret_cast<const i32x4*>(ab + 1024);
            const i32x4 lo1 = *reinterpret_cast<const i32x4*>(ab + 2048);
            const i32x4 hi1 = *reinterpret_cast<const i32x4*>(ab + 3072);
            const i32x8 a0 = __builtin_shufflevector(lo0, hi0, 0, 1, 2, 3, 4, 5, 6, 7);
            const i32x8 a1 = __builtin_shufflevector(lo1, hi1, 0, 1, 2, 3, 4, 5, 6, 7);

            f32x4 acc[4] = {{0.f, 0.f, 0.f, 0.f}, {0.f, 0.f, 0.f, 0.f},
                            {0.f, 0.f, 0.f, 0.f}, {0.f, 0.f, 0.f, 0.f}};
#pragma unroll
            for (int t = 0; t < 4; ++t)
                acc[t] = mfma_mx(a0, bfrag[t][0], acc[t]);
#pragma unroll
            for (int t = 0; t < 4; ++t)
                acc[t] = mfma_mx(a1, bfrag[t][1], acc[t]);

            const int c0 = cc_base + it * 16;
            const bool special = (c0 < wr0 + 64 && c0 + 16 > wr0) ||
                                 (c0 < p0 + 64 && c0 + 16 > p0);
            if (!special) {
#pragma unroll
                for (int t = 0; t < 4; ++t)
#pragma unroll
                    for (int j = 0; j < 4; ++j)
                        sum_exp[t] += fast_exp2(acc[t][j]);
            } else {
#pragma unroll
                for (int t = 0; t < 4; ++t) {
                    const int r = wr0 + t * 16 + l15;
#pragma unroll
                    for (int j = 0; j < 4; ++j) {
                        const int col = c0 + quad * 4 + j;
                        const float e = fast_exp2(acc[t][j]);
                        sum_exp[t] += (col == r) ? 0.f : e;               // self-diag
                        if (col == (r ^ N_HALF)) pos_acc += acc[t][j];    // positive
                    }
                }
            }
        }

        // next chunk's loads were issued a full chunk ago -> drain ~free.
        asm volatile("s_waitcnt vmcnt(0)" ::: "memory");
        __syncthreads();
        cur ^= 1;
    }

    // Per-row partial: reduce over the 4 quads (col groups), one store per row.
#pragma unroll
    for (int t = 0; t < 4; ++t) {
        float s = sum_exp[t];
        s += __shfl_xor(s, 16, 64);
        s += __shfl_xor(s, 32, 64);
        if (lane < 16)
            rowsum_part[(size_t)cs * TWO_N + wr0 + t * 16 + lane] = s;
    }

    // Positive partial: every wave writes its slot (0 if no partner overlap).
#pragma unroll
    for (int m = 1; m < 64; m <<= 1) pos_acc += __shfl_xor(pos_acc, m, 64);
    if (lane == 0) pos_part[blockIdx.x * 8 + wave] = pos_acc;
}

// ---------------------------------------------------------------------------
// Kernel 3: per-row ln(sum of 16 partials) minus ln2 * positive partials
// (2048 pos slots; slot->row mapping irrelevant for the global sum),
// block-reduced, one atomicAdd per block onto out[0] (zeroed by nrm).
// ---------------------------------------------------------------------------
__global__ __launch_bounds__(1024) void fin1_kernel(const float* __restrict__ rowsum_part,
                                                    const float* __restrict__ pos_part,
                                                    float* __restrict__ out)
{
    __shared__ float red[16];
    const int t = threadIdx.x;
    const int r = blockIdx.x * 1024 + t;
    float acc = 0.f;
#pragma unroll
    for (int cs = 0; cs < 16; ++cs)
        acc += rowsum_part[(size_t)cs * TWO_N + r];
    float v = logf(acc);
    if (r < 2048)
        v -= 0.69314718055994531f * pos_part[r];
#pragma unroll
    for (int m = 1; m < 64; m <<= 1) v += __shfl_xor(v, m, 64);
    if ((t & 63) == 0) red[t >> 6] = v;
    __syncthreads();
    if (t == 0) {
        float s = 0.f;
#pragma unroll
        for (int w = 0; w < 16; ++w) s += red[w];
        atomicAdd(out, s / (float)TWO_N);
    }
}

// ---------------------------------------------------------------------------
extern "C" void kernel_launch(void* const* d_in, const int* in_sizes, int n_in,
                              void* d_out, int out_size, void* d_ws, size_t ws_size,
                              hipStream_t stream)
{
    const float* zis = (const float*)d_in[0];
    const float* zjs = (const float*)d_in[1];

    // ws: [0,2MB) swizzled fp8; then rowsum partials [16][8192] f32 (512KB);
    //     then pos partials [2048].
    unsigned char* swz = (unsigned char*)d_ws;
    float* rowsum_part = (float*)((char*)d_ws + (size_t)TWO_N * DIMS);
    float* pos_part    = rowsum_part + (size_t)16 * TWO_N;

    nrm_kernel<<<TWO_N / 8, 256, 0, stream>>>(zis, zjs, swz, (float*)d_out);
    ntx_kernel<<<256, 512, 0, stream>>>(swz, rowsum_part, pos_part);
    fin1_kernel<<<8, 1024, 0, stream>>>(rowsum_part, pos_part, (float*)d_out);
}

// Round 22
// 81.107 us; speedup vs baseline: 1.3569x; 1.0002x over previous
//
#include <hip/hip_runtime.h>
#include <hip/hip_bf16.h>

#define TWO_N  8192
#define N_HALF 4096
#define DIMS   256

typedef float f32x4 __attribute__((ext_vector_type(4)));
typedef int   i32x4 __attribute__((ext_vector_type(4)));
typedef int   i32x8 __attribute__((ext_vector_type(8)));

// raw v_exp_f32 (args here are bounded |x| <= ~3, no denormal/range handling needed)
__device__ __forceinline__ float fast_exp2(float x) {
#if __has_builtin(__builtin_amdgcn_exp2f)
    return __builtin_amdgcn_exp2f(x);
#else
    float r; asm("v_exp_f32 %0, %1" : "=v"(r) : "v"(x)); return r;
#endif
}

// MX-scaled fp8 MFMA, K=128, unit scales (E8M0 127 = 2^0). cbsz/blgp = 0 =
// OCP e4m3. Verified R18-R21: compiles, absmax 0.0, spill-free at
// __launch_bounds__(512) (R21: 81.1us total, best).
__device__ __forceinline__ f32x4 mfma_mx(i32x8 a, i32x8 b, f32x4 c) {
    return __builtin_amdgcn_mfma_scale_f32_16x16x128_f8f6f4(
        a, b, c, 0 /*cbsz: A=fp8*/, 0 /*blgp: B=fp8*/,
        0, 0x7F /*scale_a = 1.0*/, 0, 0x7F /*scale_b = 1.0*/);
}

// async global->LDS, 16B per lane: LDS dest = wave-uniform base (HW adds
// lane*16), global src = per-lane pointer (guide §5; m97 pattern).
#define GLOAD_LDS16(g, l)                                                      \
    __builtin_amdgcn_global_load_lds(                                          \
        (const __attribute__((address_space(1))) unsigned int*)(g),            \
        (__attribute__((address_space(3))) unsigned int*)(l), 16, 0, 0)

// ---------------------------------------------------------------------------
// Kernel 1: normalize rows of reps = cat([zjs, zis]), pre-scale by
// sqrt(2*log2(e)) so the MFMA dot = (1/TEMP)*log2(e)*sim, quantize to OCP
// fp8 e4m3, and store in CONFLICT-FREE 16x16x128 fragment order (R19-R21
// layout, verified 0 bank conflicts):
// Per (16-row group g, kk=k>>7): 2048-B region at ((g*2)+kk)*2048, laid out
// as 128 x 16-B slots: slot = lane + 64*h, lane = quad*16 + row%16 (quad =
// (k%128)>>5), h = (k%32)>>4 -> a wave's two ds_read_b128 (lane*16 and
// 1024 + lane*16) are stride-16, conflict-free.
// Also zeroes out[0] for fin1's atomicAdd.
// ---------------------------------------------------------------------------
__global__ __launch_bounds__(256) void nrm_kernel(const float* __restrict__ zis,
                                                  const float* __restrict__ zjs,
                                                  unsigned char* __restrict__ swz,
                                                  float* __restrict__ out)
{
    if (blockIdx.x == 0 && threadIdx.x == 0) out[0] = 0.f;

    const int tid = threadIdx.x;
    const int l32 = tid & 31;
    const int row = blockIdx.x * 8 + (tid >> 5);
    const int k0  = l32 * 8;

    const float* src = (row < N_HALF) ? (zjs + (size_t)row * DIMS)
                                      : (zis + (size_t)(row - N_HALF) * DIMS);
    const float4 v0 = reinterpret_cast<const float4*>(src + k0)[0];
    const float4 v1 = reinterpret_cast<const float4*>(src + k0 + 4)[0];
    float ss = v0.x * v0.x + v0.y * v0.y + v0.z * v0.z + v0.w * v0.w
             + v1.x * v1.x + v1.y * v1.y + v1.z * v1.z + v1.w * v1.w;
#pragma unroll
    for (int m = 1; m < 32; m <<= 1) ss += __shfl_xor(ss, m, 64);
    // norms ~16 for N(0,1) rows; cosine eps path can never trigger
    const float inv = rsqrtf(ss) * 1.69864360045f;  // * sqrt(2*log2(e))

    // pack 8 scaled values to 8 fp8 bytes (2 ints)
    int w0 = 0, w1 = 0;
    w0 = __builtin_amdgcn_cvt_pk_fp8_f32(v0.x * inv, v0.y * inv, w0, 0);
    w0 = __builtin_amdgcn_cvt_pk_fp8_f32(v0.z * inv, v0.w * inv, w0, 1);
    w1 = __builtin_amdgcn_cvt_pk_fp8_f32(v1.x * inv, v1.y * inv, w1, 0);
    w1 = __builtin_amdgcn_cvt_pk_fp8_f32(v1.z * inv, v1.w * inv, w1, 1);

    // kk = l32>>4, quad = (l32>>2)&3, h = (l32>>1)&1, in-slot off = (l32&1)*8
    const int lane_slot = ((l32 >> 2) & 3) * 16 + (row & 15);
    const size_t byte = (size_t)((row >> 4) * 2 + (l32 >> 4)) * 2048
                      + (size_t)(lane_slot + 64 * ((l32 >> 1) & 1)) * 16
                      + (l32 & 1) * 8;
    int2 o; o.x = w0; o.y = w1;
    *reinterpret_cast<int2*>(swz + byte) = o;
}

// ---------------------------------------------------------------------------
// Kernel 2 (R21 — best measured, unchanged): MX-fp8 Gram, single dispatch
// round. 512x512 tile, grid 256 = 1 block/CU, 8 waves x 64 rows, A panel
// 128KB in 8 x 16KB chunks (2x16KB LDS dbuf, conflict-free half-split
// layout), one vmcnt(0)+barrier per chunk (loads issued a full chunk early),
// __launch_bounds__(512) for the full 256-reg budget (spill-free).
// D layout (shape-determined, m121-128): row = wr0 + t*16 + l15 (B-side),
// col = c0 + quad*4 + j (A-side).
// ---------------------------------------------------------------------------
__global__ __launch_bounds__(512) void ntx_kernel(const unsigned char* __restrict__ swz,
                                                  float* __restrict__ rowsum_part,
                                                  float* __restrict__ pos_part)
{
    __shared__ unsigned char abuf[2][16384];   // 2 x 16 KB (64-col chunk dbuf)

    const int lane = threadIdx.x & 63;
    const int wave = threadIdx.x >> 6;   // 0..7
    const int l15  = lane & 15;
    const int quad = lane >> 4;

    const int rg   = blockIdx.x & 15;    // 16 row groups of 512
    const int cs   = blockIdx.x >> 4;    // 16 col groups of 512
    const int wr0  = rg * 512 + wave * 64;
    const int p0   = wr0 ^ N_HALF;       // partner-row window (positives)

    // stage chunk c (64 cols = 4 col-16-groups x 4096 B = 16KB): 2 x 1KB
    // issues per wave (byte-copy; the fragment permutation lives inside).
    auto stage = [&](int buf, int c) {
        const unsigned char* gsrc = swz + (size_t)cs * 131072 + (size_t)c * 16384
                                  + wave * 2048 + lane * 16;
        GLOAD_LDS16(gsrc,        &abuf[buf][wave * 2048]);
        GLOAD_LDS16(gsrc + 1024, &abuf[buf][wave * 2048 + 1024]);
    };

    stage(0, 0);   // chunk 0 in flight while B fragments load

    // Hoist B (row) fragments: 4 groups of 16 rows x 2 K-chunks (K=128 each).
    // Half-split layout -> two coalesced 1KB wave reads per (t,kk); concat
    // via shufflevector (register-pair coalescing, no scratch).
    i32x8 bfrag[4][2];
#pragma unroll
    for (int t = 0; t < 4; ++t) {
        const unsigned char* bp = swz + (size_t)(((wr0 >> 4) + t) * 2) * 2048 + lane * 16;
#pragma unroll
        for (int kk = 0; kk < 2; ++kk) {
            const i32x4 lo = *reinterpret_cast<const i32x4*>(bp + kk * 2048);
            const i32x4 hi = *reinterpret_cast<const i32x4*>(bp + kk * 2048 + 1024);
            bfrag[t][kk] = __builtin_shufflevector(lo, hi, 0, 1, 2, 3, 4, 5, 6, 7);
        }
    }

    float sum_exp[4] = {0.f, 0.f, 0.f, 0.f};
    float pos_acc = 0.f;

    asm volatile("s_waitcnt vmcnt(0)" ::: "memory");
    __syncthreads();   // chunk 0 resident

    int cur = 0;
    for (int c = 0; c < 8; ++c) {
        if (c < 7) stage(cur ^ 1, c + 1);   // prefetch next chunk (lands early)

        const int cc_base = cs * 512 + c * 64;

#pragma unroll
        for (int it = 0; it < 4; ++it) {    // 4 sub-its of 16 cols
            const unsigned char* ab = &abuf[cur][it * 4096 + lane * 16];
            const i32x4 lo0 = *reinterpret_cast<const i32x4*>(ab);
            const i32x4 hi0 = *reinterpret_cast<const i32x4*>(ab + 1024);
            const i32x4 lo1 = *reinterpret_cast<const i32x4*>(ab + 2048);
            const i32x4 hi1 = *reinterpret_cast<const i32x4*>(ab + 3072);
            const i32x8 a0 = __builtin_shufflevector(lo0, hi0, 0, 1, 2, 3, 4, 5, 6, 7);
            const i32x8 a1 = __builtin_shufflevector(lo1, hi1, 0, 1, 2, 3, 4, 5, 6, 7);

            f32x4 acc[4] = {{0.f, 0.f, 0.f, 0.f}, {0.f, 0.f, 0.f, 0.f},
                            {0.f, 0.f, 0.f, 0.f}, {0.f, 0.f, 0.f, 0.f}};
#pragma unroll
            for (int t = 0; t < 4; ++t)
                acc[t] = mfma_mx(a0, bfrag[t][0], acc[t]);
#pragma unroll
            for (int t = 0; t < 4; ++t)
                acc[t] = mfma_mx(a1, bfrag[t][1], acc[t]);

            const int c0 = cc_base + it * 16;
            const bool special = (c0 < wr0 + 64 && c0 + 16 > wr0) ||
                                 (c0 < p0 + 64 && c0 + 16 > p0);
            if (!special) {
#pragma unroll
                for (int t = 0; t < 4; ++t)
#pragma unroll
                    for (int j = 0; j < 4; ++j)
                        sum_exp[t] += fast_exp2(acc[t][j]);
            } else {
#pragma unroll
                for (int t = 0; t < 4; ++t) {
                    const int r = wr0 + t * 16 + l15;
#pragma unroll
                    for (int j = 0; j < 4; ++j) {
                        const int col = c0 + quad * 4 + j;
                        const float e = fast_exp2(acc[t][j]);
                        sum_exp[t] += (col == r) ? 0.f : e;               // self-diag
                        if (col == (r ^ N_HALF)) pos_acc += acc[t][j];    // positive
                    }
                }
            }
        }

        // next chunk's loads were issued a full chunk ago -> drain ~free.
        asm volatile("s_waitcnt vmcnt(0)" ::: "memory");
        __syncthreads();
        cur ^= 1;
    }

    // Per-row partial: reduce over the 4 quads (col groups), one store per row.
#pragma unroll
    for (int t = 0; t < 4; ++t) {
        float s = sum_exp[t];
        s += __shfl_xor(s, 16, 64);
        s += __shfl_xor(s, 32, 64);
        if (lane < 16)
            rowsum_part[(size_t)cs * TWO_N + wr0 + t * 16 + lane] = s;
    }

    // Positive partial: every wave writes its slot (0 if no partner overlap).
#pragma unroll
    for (int m = 1; m < 64; m <<= 1) pos_acc += __shfl_xor(pos_acc, m, 64);
    if (lane == 0) pos_part[blockIdx.x * 8 + wave] = pos_acc;
}

// ---------------------------------------------------------------------------
// Kernel 3 (regeometry 8x1024 -> 64x128): per-row ln(sum of 16 partials)
// minus ln2 * positive partials (2048 pos slots; slot->row mapping is
// irrelevant for the global sum), block-reduced, one atomicAdd per block
// onto out[0] (zeroed by nrm). 8 blocks used only 8 of 256 CUs with each
// thread latency-exposed on 16 strided reads + logf; 64 blocks spread the
// same work over 8x more CUs (~2.5us -> <1us). Per-row math order unchanged.
// ---------------------------------------------------------------------------
__global__ __launch_bounds__(128) void fin1_kernel(const float* __restrict__ rowsum_part,
                                                   const float* __restrict__ pos_part,
                                                   float* __restrict__ out)
{
    __shared__ float red[2];
    const int t = threadIdx.x;
    const int r = blockIdx.x * 128 + t;
    float acc = 0.f;
#pragma unroll
    for (int cs = 0; cs < 16; ++cs)
        acc += rowsum_part[(size_t)cs * TWO_N + r];
    float v = logf(acc);
    if (r < 2048)
        v -= 0.69314718055994531f * pos_part[r];
#pragma unroll
    for (int m = 1; m < 64; m <<= 1) v += __shfl_xor(v, m, 64);
    if ((t & 63) == 0) red[t >> 6] = v;
    __syncthreads();
    if (t == 0)
        atomicAdd(out, (red[0] + red[1]) / (float)TWO_N);
}

// ---------------------------------------------------------------------------
extern "C" void kernel_launch(void* const* d_in, const int* in_sizes, int n_in,
                              void* d_out, int out_size, void* d_ws, size_t ws_size,
                              hipStream_t stream)
{
    const float* zis = (const float*)d_in[0];
    const float* zjs = (const float*)d_in[1];

    // ws: [0,2MB) swizzled fp8; then rowsum partials [16][8192] f32 (512KB);
    //     then pos partials [2048].
    unsigned char* swz = (unsigned char*)d_ws;
    float* rowsum_part = (float*)((char*)d_ws + (size_t)TWO_N * DIMS);
    float* pos_part    = rowsum_part + (size_t)16 * TWO_N;

    nrm_kernel<<<TWO_N / 8, 256, 0, stream>>>(zis, zjs, swz, (float*)d_out);
    ntx_kernel<<<256, 512, 0, stream>>>(swz, rowsum_part, pos_part);
    fin1_kernel<<<64, 128, 0, stream>>>(rowsum_part, pos_part, (float*)d_out);
}